// Round 2
// baseline (1556.221 us; speedup 1.0000x reference)
//
#include <hip/hip_runtime.h>
#include <math.h>

#define NB 1000      // graphs
#define NN 100       // nodes per graph
#define EPG 1000     // edges per graph
#define FIN 14
#define HD 128
#define KP1 80
#define KP2 64

// LDS layout (float offsets)
#define OFF_ADJ   0                       // [100][100] = 10000
#define OFF_HS    10000                   // [100][128] = 12800
#define OFF_BC    22800                   // [100][32]  = 3200 (aliases xg[1400], agg1[1400])
#define OFF_SC    26000                   // 100
#define OFF_MK1   26100                   // 100
#define OFF_MK2   26200                   // 100
#define OFF_P1S   26300                   // 128
#define OFF_P2S   26428                   // 128
#define OFF_ZSH   26556                   // 256
#define OFF_ZRED  26812                   // 256
#define OFF_Z1    27068                   // 128
#define OFF_INV   27196                   // 2
#define SMEM_FLOATS 27200
#define SMEM_BYTES (SMEM_FLOATS * 4)

__global__ __launch_bounds__(256, 1) void fused_gnn(
    const float* __restrict__ x, const int* __restrict__ ei,
    const float* __restrict__ Wrel1, const float* __restrict__ Wroot1,
    const float* __restrict__ b1, const float* __restrict__ p1,
    const float* __restrict__ Wrel2, const float* __restrict__ Wroot2,
    const float* __restrict__ b2, const float* __restrict__ p2,
    const float* __restrict__ l1w, const float* __restrict__ l1b,
    const float* __restrict__ l2w, const float* __restrict__ l2b,
    const float* __restrict__ l3w, const float* __restrict__ l3b,
    float* __restrict__ out)
{
    extern __shared__ float smf[];
    float* Adj  = smf + OFF_ADJ;
    float* Hs   = smf + OFF_HS;
    float* Bc   = smf + OFF_BC;
    float* xg   = Bc;            // [100][14], dead after conv1
    float* agg1 = Bc + 1400;     // [100][14], dead after conv1
    float* sc   = smf + OFF_SC;
    float* mk1  = smf + OFF_MK1;
    float* mk2  = smf + OFF_MK2;
    float* p1s  = smf + OFF_P1S;
    float* p2s  = smf + OFF_P2S;
    float* zsh  = smf + OFF_ZSH;
    float* zred = smf + OFF_ZRED;
    float* z1   = smf + OFF_Z1;
    float* inv  = smf + OFF_INV;

    const int tid = threadIdx.x;
    const int g = blockIdx.x;
    const int bn = g * NN;
    const int* srcp = ei + g * EPG;
    const int* dstp = ei + NB * EPG + g * EPG;

    // ---------------- P0: init, Adj build, norm reductions ----------------
    for (int t = tid; t < NN * NN; t += 256) Adj[t] = 0.f;
    for (int t = tid; t < NN * FIN; t += 256) xg[t] = x[bn * FIN + t];
    {
        float v;
        if (tid < 128) { v = p1[tid]; p1s[tid] = v; }
        else           { v = p2[tid - 128]; p2s[tid - 128] = v; }
        zred[tid] = v * v;
    }
    __syncthreads();

    // build multiplicity adjacency (float counts; exact in fp32)
    for (int e = tid; e < EPG; e += 256) {
        int sl = srcp[e] - bn;
        int dl = dstp[e] - bn;
        atomicAdd(&Adj[dl * NN + sl], 1.f);
    }
    // parallel tree-reduce both norm squares (zred[0:128]=p1, zred[128:256]=p2)
    for (int s = 64; s > 0; s >>= 1) {
        __syncthreads();
        if (tid < s) zred[tid] += zred[tid + s];
        else if (tid >= 128 && tid < 128 + s) zred[tid] += zred[tid + s];
    }
    __syncthreads();
    if (tid == 0) { inv[0] = rsqrtf(zred[0]); inv[1] = rsqrtf(zred[128]); }
    __syncthreads();

    // ---------------- P1: agg1 = Adj @ xg  [100][14] ----------------
    for (int o = tid; o < NN * FIN; o += 256) {
        int i = o / FIN, f = o - i * FIN;
        const float* arow = Adj + i * NN;
        float s = 0.f;
        for (int k = 0; k < NN; ++k) s += arow[k] * xg[k * FIN + f];
        agg1[o] = s;
    }
    __syncthreads();

    // ---------------- P2: h1 = relu(agg1@Wrel1 + xg@Wroot1 + b1) ----------------
    {
        const int j = tid & 127;
        float wr[FIN], wo[FIN];
        for (int k = 0; k < FIN; ++k) { wr[k] = Wrel1[k * HD + j]; wo[k] = Wroot1[k * HD + j]; }
        const float bb = b1[j];
        for (int i = tid >> 7; i < NN; i += 2) {
            float s = bb;
            for (int k = 0; k < FIN; ++k)
                s += agg1[i * FIN + k] * wr[k] + xg[i * FIN + k] * wo[k];
            Hs[i * HD + j] = fmaxf(s, 0.f);
        }
    }
    __syncthreads();

    // ---------------- P3: pool1 + readout1 ----------------
    if (tid < NN) {
        float d = 0.f;
        for (int k = 0; k < HD; ++k) { int kk = (k + tid) & 127; d += Hs[tid * HD + kk] * p1s[kk]; }
        sc[tid] = tanhf(d * inv[0]);
    }
    __syncthreads();
    if (tid < NN) {
        float si = sc[tid]; int cnt = 0;
        for (int j2 = 0; j2 < NN; ++j2) cnt += (sc[j2] > si) ? 1 : 0;
        mk1[tid] = (cnt < KP1) ? 1.f : 0.f;
    }
    __syncthreads();
    for (int o = tid; o < NN * HD; o += 256) { int i = o >> 7; Hs[o] *= sc[i] * mk1[i]; }
    __syncthreads();
    if (tid < HD) {
        float mean = 0.f, mx = -1e30f;
        for (int i = 0; i < NN; ++i) {
            float v = Hs[i * HD + tid];
            mean += v;
            if (mk1[i] > 0.f && v > mx) mx = v;
        }
        zsh[tid] = mean * (1.f / KP1);
        zsh[HD + tid] = mx;
    }
    __syncthreads();

    // ---------------- P4: conv2 = relu(Adj@Hs@Wrel2 + Hs@Wroot2 + b2) ----------------
    const int tr = tid >> 5, tc = tid & 31;
    const int i0 = tr * 13, j0 = tc * 4;
    const float4* Wrel2v  = (const float4*)Wrel2;
    const float4* Wroot2v = (const float4*)Wroot2;

    float acc[13][4];
    {
        float4 bv = ((const float4*)b2)[tc];
#pragma unroll
        for (int r = 0; r < 13; ++r) { acc[r][0] = bv.x; acc[r][1] = bv.y; acc[r][2] = bv.z; acc[r][3] = bv.w; }
    }
    // root pass: acc += Hs @ Wroot2
    for (int k = 0; k < HD; ++k) {
        float4 w = Wroot2v[k * 32 + tc];
#pragma unroll
        for (int r = 0; r < 13; ++r) {
            int i = i0 + r;
            if (i < NN) {
                float a = Hs[i * HD + k];
                acc[r][0] += a * w.x; acc[r][1] += a * w.y; acc[r][2] += a * w.z; acc[r][3] += a * w.w;
            }
        }
    }
    // rel pass in 4 column-chunks of 32: Bc = Adj @ Hs[:, c*32:+32]; acc += Bc @ Wrel2[c*32:+32, :]
    for (int c = 0; c < 4; ++c) {
        __syncthreads();
        {
            const int jj = tid & 31;
            float a2[13];
#pragma unroll
            for (int r = 0; r < 13; ++r) a2[r] = 0.f;
            for (int k = 0; k < NN; ++k) {
                float hv = Hs[k * HD + c * 32 + jj];
#pragma unroll
                for (int r = 0; r < 13; ++r) {
                    int i = i0 + r;
                    if (i < NN) a2[r] += Adj[i * NN + k] * hv;
                }
            }
#pragma unroll
            for (int r = 0; r < 13; ++r) { int i = i0 + r; if (i < NN) Bc[i * 32 + jj] = a2[r]; }
        }
        __syncthreads();
        for (int kk = 0; kk < 32; ++kk) {
            int k = c * 32 + kk;
            float4 w = Wrel2v[k * 32 + tc];
#pragma unroll
            for (int r = 0; r < 13; ++r) {
                int i = i0 + r;
                if (i < NN) {
                    float a = Bc[i * 32 + kk];
                    acc[r][0] += a * w.x; acc[r][1] += a * w.y; acc[r][2] += a * w.z; acc[r][3] += a * w.w;
                }
            }
        }
    }
    __syncthreads();   // all reads of Hs done; safe to overwrite with h2
#pragma unroll
    for (int r = 0; r < 13; ++r) {
        int i = i0 + r;
        if (i < NN) {
            Hs[i * HD + j0 + 0] = fmaxf(acc[r][0], 0.f);
            Hs[i * HD + j0 + 1] = fmaxf(acc[r][1], 0.f);
            Hs[i * HD + j0 + 2] = fmaxf(acc[r][2], 0.f);
            Hs[i * HD + j0 + 3] = fmaxf(acc[r][3], 0.f);
        }
    }
    __syncthreads();

    // ---------------- P5: pool2 + readout2 ----------------
    if (tid < NN) {
        float sv;
        if (mk1[tid] > 0.f) {
            float d = 0.f;
            for (int k = 0; k < HD; ++k) { int kk = (k + tid) & 127; d += Hs[tid * HD + kk] * p2s[kk]; }
            sv = tanhf(d * inv[1]);
        } else sv = -1e30f;
        sc[tid] = sv;
    }
    __syncthreads();
    if (tid < NN) {
        float si = sc[tid]; int cnt = 0;
        for (int j2 = 0; j2 < NN; ++j2) cnt += (sc[j2] > si) ? 1 : 0;
        mk2[tid] = (mk1[tid] > 0.f && cnt < KP2) ? 1.f : 0.f;
    }
    __syncthreads();
    for (int o = tid; o < NN * HD; o += 256) { int i = o >> 7; Hs[o] *= sc[i] * mk2[i]; }
    __syncthreads();
    if (tid < HD) {
        float mean = 0.f, mx = -1e30f;
        for (int i = 0; i < NN; ++i) {
            float v = Hs[i * HD + tid];
            mean += v;
            if (mk2[i] > 0.f && v > mx) mx = v;
        }
        zsh[tid] += mean * (1.f / KP2);
        zsh[HD + tid] += mx;
    }
    __syncthreads();

    // ---------------- P6: MLP + log_softmax ----------------
    {   // l1: 256 -> 128 (split k over 2 halves)
        const int j = tid & 127, h = tid >> 7;
        float a = 0.f;
        for (int kk = 0; kk < 128; ++kk) {
            int k = h * 128 + kk;
            a += zsh[k] * l1w[k * HD + j];
        }
        zred[tid] = a;
    }
    __syncthreads();
    if (tid < HD) z1[tid] = fmaxf(zred[tid] + zred[128 + tid] + l1b[tid], 0.f);
    __syncthreads();
    if (tid < 128) {   // l2: 128 -> 32 (split k over 4 quarters)
        const int o = tid & 31, q = tid >> 5;
        float a = 0.f;
        for (int kk = 0; kk < 32; ++kk) {
            int k = q * 32 + kk;
            a += z1[k] * l2w[k * 32 + o];
        }
        zred[tid] = a;
    }
    __syncthreads();
    if (tid < 32) {
        float v = zred[tid] + zred[32 + tid] + zred[64 + tid] + zred[96 + tid] + l2b[tid];
        zred[128 + tid] = fmaxf(v, 0.f);
    }
    __syncthreads();
    if (tid == 0) {
        float o0 = l3b[0], o1 = l3b[1];
        for (int k = 0; k < 32; ++k) {
            float v = zred[128 + k];
            o0 += v * l3w[2 * k];
            o1 += v * l3w[2 * k + 1];
        }
        float m = fmaxf(o0, o1);
        float l = m + logf(expf(o0 - m) + expf(o1 - m));
        out[g * 2 + 0] = o0 - l;
        out[g * 2 + 1] = o1 - l;
    }
}

extern "C" void kernel_launch(void* const* d_in, const int* in_sizes, int n_in,
                              void* d_out, int out_size, void* d_ws, size_t ws_size,
                              hipStream_t stream)
{
    const float* x      = (const float*)d_in[0];
    const int*   ei     = (const int*)d_in[1];
    const float* Wrel1  = (const float*)d_in[2];
    const float* Wroot1 = (const float*)d_in[3];
    const float* b1     = (const float*)d_in[4];
    const float* p1     = (const float*)d_in[5];
    const float* Wrel2  = (const float*)d_in[6];
    const float* Wroot2 = (const float*)d_in[7];
    const float* b2     = (const float*)d_in[8];
    const float* p2     = (const float*)d_in[9];
    const float* l1w    = (const float*)d_in[10];
    const float* l1b    = (const float*)d_in[11];
    const float* l2w    = (const float*)d_in[12];
    const float* l2b    = (const float*)d_in[13];
    const float* l3w    = (const float*)d_in[14];
    const float* l3b    = (const float*)d_in[15];
    float* out = (float*)d_out;

    // allow >64KB dynamic LDS (no-op if already permitted); not a stream op
    (void)hipFuncSetAttribute((const void*)fused_gnn,
                              hipFuncAttributeMaxDynamicSharedMemorySize, SMEM_BYTES);

    fused_gnn<<<dim3(NB), dim3(256), SMEM_BYTES, stream>>>(
        x, ei, Wrel1, Wroot1, b1, p1, Wrel2, Wroot2, b2, p2,
        l1w, l1b, l2w, l2b, l3w, l3b, out);
}

// Round 3
// 976.249 us; speedup vs baseline: 1.5941x; 1.5941x over previous
//
#include <hip/hip_runtime.h>
#include <math.h>

#define NB 1000      // graphs
#define NN 100       // nodes per graph
#define NNP 104      // padded rows (reg-tile 8*13)
#define EPG 1000     // edges per graph
#define FIN 14
#define HD 128
#define KP1 80
#define KP2 64

// LDS float offsets
#define O_HS   0                    // [104][128] = 13312
#define O_CB   13312                // 3200: conv1 {xg[100][16], ag[100][16]} / conv2 chunk [100][32]
#define O_SE   16512                // 1000 uints: packed (src | dst<<16)
#define O_SC   17512                // 100
#define O_MK1  17612                // 100
#define O_MK2  17712                // 100
#define O_P1   17812                // 128
#define O_P2   17940                // 128
#define O_ZSH  18068                // 256
#define O_ZRD  18324                // 256
#define O_Z1   18580                // 128
#define O_INV  18708                // 2
#define NSM    18712
#define SMEM_BYTES (NSM * 4)        // 74848 B ~ 73.1 KB -> 2 blocks/CU

__global__ __launch_bounds__(256, 2) void fused_gnn(
    const float* __restrict__ x, const int* __restrict__ ei,
    const float* __restrict__ Wrel1, const float* __restrict__ Wroot1,
    const float* __restrict__ b1, const float* __restrict__ p1,
    const float* __restrict__ Wrel2, const float* __restrict__ Wroot2,
    const float* __restrict__ b2, const float* __restrict__ p2,
    const float* __restrict__ l1w, const float* __restrict__ l1b,
    const float* __restrict__ l2w, const float* __restrict__ l2b,
    const float* __restrict__ l3w, const float* __restrict__ l3b,
    float* __restrict__ out)
{
    extern __shared__ float smf[];
    float* Hs  = smf + O_HS;
    float* CB  = smf + O_CB;
    float* xg  = CB;                 // [100][16] (cols 14,15 zero)
    float* ag  = CB + 1600;          // [100][16]
    unsigned int* se = (unsigned int*)(smf + O_SE);
    float* sc  = smf + O_SC;
    float* mk1 = smf + O_MK1;
    float* mk2 = smf + O_MK2;
    float* p1s = smf + O_P1;
    float* p2s = smf + O_P2;
    float* zsh = smf + O_ZSH;
    float* zrd = smf + O_ZRD;
    float* z1  = smf + O_Z1;
    float* inv = smf + O_INV;

    const int tid = threadIdx.x;
    const int g = blockIdx.x;
    const int bn = g * NN;
    const int* srcp = ei + g * EPG;
    const int* dstp = ei + NB * EPG + g * EPG;

    // ---------- P0: stage xg (padded), zero ag + Hs pad rows, edges, p-norms ----------
    for (int t = tid; t < 1600; t += 256) {
        int i = t >> 4, f = t & 15;
        xg[t] = (f < FIN) ? x[bn * FIN + i * FIN + f] : 0.f;
        ag[t] = 0.f;
    }
    for (int t = tid; t < (NNP - NN) * HD; t += 256) Hs[NN * HD + t] = 0.f;
    for (int e = tid; e < EPG; e += 256) {
        unsigned int sl = (unsigned int)(srcp[e] - bn);
        unsigned int dl = (unsigned int)(dstp[e] - bn);
        se[e] = sl | (dl << 16);
    }
    {
        float v;
        if (tid < 128) { v = p1[tid]; p1s[tid] = v; }
        else           { v = p2[tid - 128]; p2s[tid - 128] = v; }
        zrd[tid] = v * v;
    }
    for (int s = 64; s > 0; s >>= 1) {
        __syncthreads();
        if (tid < s) zrd[tid] += zrd[tid + s];
        else if (tid >= 128 && tid < 128 + s) zrd[tid] += zrd[tid + s];
    }
    __syncthreads();
    if (tid == 0) { inv[0] = rsqrtf(zrd[0]); inv[1] = rsqrtf(zrd[128]); }
    __syncthreads();

    // ---------- P1: conv1 edge aggregation: ag[dl][f] += xg[sl][f] ----------
    {
        const int jj = tid & 15, eg = tid >> 4;   // 16 edges in flight
        if (jj < FIN) {
            for (int e = eg; e < EPG; e += 16) {
                unsigned int p = se[e];
                int sl = (int)(p & 0xffffu), dl = (int)(p >> 16);
                atomicAdd(&ag[dl * 16 + jj], xg[sl * 16 + jj]);
            }
        }
    }
    __syncthreads();

    // ---------- P2: h1 = relu(ag@Wrel1 + xg@Wroot1 + b1) ----------
    {
        const int j = tid & 127;
        float wr[FIN], wo[FIN];
#pragma unroll
        for (int k = 0; k < FIN; ++k) { wr[k] = Wrel1[k * HD + j]; wo[k] = Wroot1[k * HD + j]; }
        const float bb = b1[j];
        for (int i = tid >> 7; i < NN; i += 2) {
            float s = bb;
#pragma unroll
            for (int k = 0; k < FIN; ++k)
                s += ag[i * 16 + k] * wr[k] + xg[i * 16 + k] * wo[k];
            Hs[i * HD + j] = fmaxf(s, 0.f);
        }
    }
    __syncthreads();

    // ---------- P3: pool1 (score, top-80, scale) + readout1 ----------
    if (tid < NN) {
        float d = 0.f;
        for (int k = 0; k < HD; ++k) { int kk = (k + tid) & 127; d += Hs[tid * HD + kk] * p1s[kk]; }
        sc[tid] = tanhf(d * inv[0]);
    }
    __syncthreads();
    if (tid < NN) {
        float si = sc[tid]; int cnt = 0;
        for (int j2 = 0; j2 < NN; ++j2) cnt += (sc[j2] > si) ? 1 : 0;
        mk1[tid] = (cnt < KP1) ? 1.f : 0.f;
    }
    __syncthreads();
    for (int o = tid; o < NN * HD; o += 256) { int i = o >> 7; Hs[o] *= sc[i] * mk1[i]; }
    __syncthreads();
    if (tid < HD) {
        float mean = 0.f, mx = -1e30f;
        for (int i = 0; i < NN; ++i) {
            float v = Hs[i * HD + tid];
            mean += v;
            if (mk1[i] > 0.f && v > mx) mx = v;
        }
        zsh[tid] = mean * (1.f / KP1);
        zsh[HD + tid] = mx;
    }
    // no sync needed here for readers of Hs (read-only until chunk loop's syncs)

    // ---------- P4: conv2: acc = b2 + Hs@Wroot2 + sum_c (edge-agg chunk)@Wrel2 ----------
    const int tr = tid >> 5, tc = tid & 31;
    const int i0 = tr * 13, j0 = tc * 4;
    const float4* Wrel2v  = (const float4*)Wrel2;
    const float4* Wroot2v = (const float4*)Wroot2;

    float acc[13][4];
    {
        float4 bv = ((const float4*)b2)[tc];
#pragma unroll
        for (int r = 0; r < 13; ++r) { acc[r][0] = bv.x; acc[r][1] = bv.y; acc[r][2] = bv.z; acc[r][3] = bv.w; }
    }
    // root pass (rows padded to 104: no guards; pad rows are zero)
#pragma unroll 8
    for (int k = 0; k < HD; ++k) {
        float4 w = Wroot2v[k * 32 + tc];
#pragma unroll
        for (int r = 0; r < 13; ++r) {
            float a = Hs[(i0 + r) * HD + k];
            acc[r][0] += a * w.x; acc[r][1] += a * w.y; acc[r][2] += a * w.z; acc[r][3] += a * w.w;
        }
    }
    // rel pass: 4 chunks of 32 columns
    for (int c = 0; c < 4; ++c) {
        __syncthreads();                     // CB readers (prev FMA / conv1) done
        for (int t = tid; t < 3200; t += 256) CB[t] = 0.f;
        __syncthreads();
        {
            const int jj = tid & 31, eg2 = tid >> 5;   // 8 edges in flight
            const int cb = c * 32 + jj;
            for (int e = eg2; e < EPG; e += 8) {
                unsigned int p = se[e];
                int sl = (int)(p & 0xffffu), dl = (int)(p >> 16);
                atomicAdd(&CB[dl * 32 + jj], Hs[sl * HD + cb]);
            }
        }
        __syncthreads();
#pragma unroll 8
        for (int kk = 0; kk < 32; ++kk) {
            float4 w = Wrel2v[(c * 32 + kk) * 32 + tc];
#pragma unroll
            for (int r = 0; r < 13; ++r) {
                float a = (i0 + r < NN) ? CB[(i0 + r) * 32 + kk] : 0.f;
                acc[r][0] += a * w.x; acc[r][1] += a * w.y; acc[r][2] += a * w.z; acc[r][3] += a * w.w;
            }
        }
    }
    __syncthreads();                          // all atomic readers of Hs done
    // write h2 = relu(acc) into Hs (pad rows written, never read)
#pragma unroll
    for (int r = 0; r < 13; ++r) {
        int i = i0 + r;
        Hs[i * HD + j0 + 0] = fmaxf(acc[r][0], 0.f);
        Hs[i * HD + j0 + 1] = fmaxf(acc[r][1], 0.f);
        Hs[i * HD + j0 + 2] = fmaxf(acc[r][2], 0.f);
        Hs[i * HD + j0 + 3] = fmaxf(acc[r][3], 0.f);
    }
    __syncthreads();

    // ---------- P5: pool2 (score gated by mk1, top-64, scale) + readout2 ----------
    if (tid < NN) {
        float sv;
        if (mk1[tid] > 0.f) {
            float d = 0.f;
            for (int k = 0; k < HD; ++k) { int kk = (k + tid) & 127; d += Hs[tid * HD + kk] * p2s[kk]; }
            sv = tanhf(d * inv[1]);
        } else sv = -1e30f;
        sc[tid] = sv;
    }
    __syncthreads();
    if (tid < NN) {
        float si = sc[tid]; int cnt = 0;
        for (int j2 = 0; j2 < NN; ++j2) cnt += (sc[j2] > si) ? 1 : 0;
        mk2[tid] = (mk1[tid] > 0.f && cnt < KP2) ? 1.f : 0.f;
    }
    __syncthreads();
    for (int o = tid; o < NN * HD; o += 256) { int i = o >> 7; Hs[o] *= sc[i] * mk2[i]; }
    __syncthreads();
    if (tid < HD) {
        float mean = 0.f, mx = -1e30f;
        for (int i = 0; i < NN; ++i) {
            float v = Hs[i * HD + tid];
            mean += v;
            if (mk2[i] > 0.f && v > mx) mx = v;
        }
        zsh[tid] += mean * (1.f / KP2);
        zsh[HD + tid] += mx;
    }
    __syncthreads();

    // ---------- P6: MLP + log_softmax ----------
    {   // l1: 256 -> 128, k split over 2 halves
        const int j = tid & 127, h = tid >> 7;
        float a = 0.f;
        for (int kk = 0; kk < 128; ++kk) {
            int k = h * 128 + kk;
            a += zsh[k] * l1w[k * HD + j];
        }
        zrd[tid] = a;
    }
    __syncthreads();
    if (tid < HD) z1[tid] = fmaxf(zrd[tid] + zrd[128 + tid] + l1b[tid], 0.f);
    __syncthreads();
    if (tid < 128) {   // l2: 128 -> 32, k split over 4 quarters
        const int o = tid & 31, q = tid >> 5;
        float a = 0.f;
        for (int kk = 0; kk < 32; ++kk) {
            int k = q * 32 + kk;
            a += z1[k] * l2w[k * 32 + o];
        }
        zrd[tid] = a;
    }
    __syncthreads();
    if (tid < 32) {
        float v = zrd[tid] + zrd[32 + tid] + zrd[64 + tid] + zrd[96 + tid] + l2b[tid];
        zrd[128 + tid] = fmaxf(v, 0.f);
    }
    __syncthreads();
    if (tid == 0) {
        float o0 = l3b[0], o1 = l3b[1];
        for (int k = 0; k < 32; ++k) {
            float v = zrd[128 + k];
            o0 += v * l3w[2 * k];
            o1 += v * l3w[2 * k + 1];
        }
        float m = fmaxf(o0, o1);
        float l = m + logf(expf(o0 - m) + expf(o1 - m));
        out[g * 2 + 0] = o0 - l;
        out[g * 2 + 1] = o1 - l;
    }
}

extern "C" void kernel_launch(void* const* d_in, const int* in_sizes, int n_in,
                              void* d_out, int out_size, void* d_ws, size_t ws_size,
                              hipStream_t stream)
{
    const float* x      = (const float*)d_in[0];
    const int*   ei     = (const int*)d_in[1];
    const float* Wrel1  = (const float*)d_in[2];
    const float* Wroot1 = (const float*)d_in[3];
    const float* b1     = (const float*)d_in[4];
    const float* p1     = (const float*)d_in[5];
    const float* Wrel2  = (const float*)d_in[6];
    const float* Wroot2 = (const float*)d_in[7];
    const float* b2     = (const float*)d_in[8];
    const float* p2     = (const float*)d_in[9];
    const float* l1w    = (const float*)d_in[10];
    const float* l1b    = (const float*)d_in[11];
    const float* l2w    = (const float*)d_in[12];
    const float* l2b    = (const float*)d_in[13];
    const float* l3w    = (const float*)d_in[14];
    const float* l3b    = (const float*)d_in[15];
    float* out = (float*)d_out;

    (void)hipFuncSetAttribute((const void*)fused_gnn,
                              hipFuncAttributeMaxDynamicSharedMemorySize, SMEM_BYTES);

    fused_gnn<<<dim3(NB), dim3(256), SMEM_BYTES, stream>>>(
        x, ei, Wrel1, Wroot1, b1, p1, Wrel2, Wroot2, b2, p2,
        l1w, l1b, l2w, l2b, l3w, l3b, out);
}

// Round 4
// 864.948 us; speedup vs baseline: 1.7992x; 1.1287x over previous
//
#include <hip/hip_runtime.h>
#include <math.h>

#define NB 1000      // graphs
#define NN 100       // nodes per graph
#define NNP 112      // padded rows (16 row-groups * 7)
#define EPG 1000     // edges per graph
#define FIN 14
#define HD 128
#define KP1 80
#define KP2 64
#define NT 512       // threads per block

// LDS float offsets
#define O_HS   0                        // [112][128] = 14336
#define O_CB   14336                    // [112][32] = 3584 (alias xg[1600]+ag[1600]; scratch; z1/z2 in MLP)
#define O_SE   17920                    // 1000 packed edges
#define O_SC   18920                    // 100
#define O_MK1  19020                    // 100
#define O_MK2  19120                    // 100
#define O_P1   19220                    // 128
#define O_P2   19348                    // 128
#define O_ZSH  19476                    // 256
#define O_ZRD  19732                    // 512
#define O_INV  20244                    // 2
#define NSM    20246
#define SMEM_BYTES (NSM * 4)            // 80984 B -> 2 blocks/CU (160 KB pool)

__global__ __launch_bounds__(NT, 4) void fused_gnn(
    const float* __restrict__ x, const int* __restrict__ ei,
    const float* __restrict__ Wrel1, const float* __restrict__ Wroot1,
    const float* __restrict__ b1, const float* __restrict__ p1,
    const float* __restrict__ Wrel2, const float* __restrict__ Wroot2,
    const float* __restrict__ b2, const float* __restrict__ p2,
    const float* __restrict__ l1w, const float* __restrict__ l1b,
    const float* __restrict__ l2w, const float* __restrict__ l2b,
    const float* __restrict__ l3w, const float* __restrict__ l3b,
    float* __restrict__ out)
{
    extern __shared__ float smf[];
    float* Hs  = smf + O_HS;
    float* CB  = smf + O_CB;
    float* xg  = CB;                 // [100][16] (cols 14,15 zero)
    float* ag  = CB + 1600;          // [100][16]
    unsigned int* se = (unsigned int*)(smf + O_SE);
    float* sc  = smf + O_SC;
    float* mk1 = smf + O_MK1;
    float* mk2 = smf + O_MK2;
    float* p1s = smf + O_P1;
    float* p2s = smf + O_P2;
    float* zsh = smf + O_ZSH;
    float* zrd = smf + O_ZRD;
    float* inv = smf + O_INV;

    const int tid = threadIdx.x;
    const int g = blockIdx.x;
    const int bn = g * NN;
    const int* srcp = ei + g * EPG;
    const int* dstp = ei + NB * EPG + g * EPG;

    // ---------- P0: stage xg/ag (padded 16), Hs pad rows, edges, p vectors+norms ----------
    for (int t = tid; t < 1600; t += NT) {
        int i = t >> 4, f = t & 15;
        xg[t] = (f < FIN) ? x[bn * FIN + i * FIN + f] : 0.f;
        ag[t] = 0.f;
    }
    for (int t = tid; t < (NNP - NN) * HD; t += NT) Hs[NN * HD + t] = 0.f;
    for (int e = tid; e < EPG; e += NT) {
        unsigned int sl = (unsigned int)(srcp[e] - bn);
        unsigned int dl = (unsigned int)(dstp[e] - bn);
        se[e] = sl | (dl << 16);
    }
    if (tid < 128) { p1s[tid] = p1[tid]; p2s[tid] = p2[tid]; }
    if (tid < 64) {
        float a = p1[tid], b = p1[tid + 64];
        float v = a * a + b * b;
        for (int s = 1; s < 64; s <<= 1) v += __shfl_xor(v, s);
        if (tid == 0) inv[0] = rsqrtf(v);
    } else if (tid < 128) {
        int l = tid - 64;
        float a = p2[l], b = p2[l + 64];
        float v = a * a + b * b;
        for (int s = 1; s < 64; s <<= 1) v += __shfl_xor(v, s);
        if (l == 0) inv[1] = rsqrtf(v);
    }
    __syncthreads();

    // ---------- P1: conv1 edge agg: ag[dl][f] += xg[sl][f]  (32 edges in flight) ----------
    {
        const int jj = tid & 15, eg = tid >> 4;
        if (jj < FIN) {
            for (int e = eg; e < EPG; e += 32) {
                unsigned int p = se[e];
                int sl = (int)(p & 0xffffu), dl = (int)(p >> 16);
                atomicAdd(&ag[dl * 16 + jj], xg[sl * 16 + jj]);
            }
        }
    }
    __syncthreads();

    // ---------- P2: h1 = relu(ag@Wrel1 + xg@Wroot1 + b1) ----------
    {
        const int j = tid & 127;
        float wr[FIN], wo[FIN];
#pragma unroll
        for (int k = 0; k < FIN; ++k) { wr[k] = Wrel1[k * HD + j]; wo[k] = Wroot1[k * HD + j]; }
        const float bb = b1[j];
        for (int i = tid >> 7; i < NN; i += 4) {
            float s = bb;
#pragma unroll
            for (int k = 0; k < FIN; ++k)
                s += ag[i * 16 + k] * wr[k] + xg[i * 16 + k] * wo[k];
            Hs[i * HD + j] = fmaxf(s, 0.f);
        }
    }
    __syncthreads();

    // ---------- P3: pool1 score (4 lanes/row, skewed) ----------
    if (tid < 400) {
        const int row = tid >> 2, q = tid & 3;
        float d = 0.f;
        for (int kk = 0; kk < 32; ++kk) {
            int k = q * 32 + ((kk + tid) & 31);
            d += Hs[row * HD + k] * p1s[k];
        }
        d += __shfl_xor(d, 1);
        d += __shfl_xor(d, 2);
        if (q == 0) sc[row] = tanhf(d * inv[0]);
    }
    __syncthreads();
    if (tid < NN) {
        float si = sc[tid]; int cnt = 0;
        for (int j2 = 0; j2 < NN; ++j2) cnt += (sc[j2] > si) ? 1 : 0;
        mk1[tid] = (cnt < KP1) ? 1.f : 0.f;
    }
    __syncthreads();
    for (int o = tid; o < NN * HD; o += NT) { int i = o >> 7; Hs[o] *= sc[i] * mk1[i]; }
    __syncthreads();
    // readout1 partials: col = tid&127, 4 row-chunks of 25
    {
        const int col = tid & 127, ch = tid >> 7;
        float mean = 0.f, mx = -1e30f;
        for (int i = ch * 25; i < ch * 25 + 25; ++i) {
            float v = Hs[i * HD + col];
            mean += v;
            if (mk1[i] > 0.f && v > mx) mx = v;
        }
        zrd[tid] = mean; CB[tid] = mx;
    }
    __syncthreads();
    if (tid < HD) {
        float mean = zrd[tid] + zrd[128 + tid] + zrd[256 + tid] + zrd[384 + tid];
        float mx = fmaxf(fmaxf(CB[tid], CB[128 + tid]), fmaxf(CB[256 + tid], CB[384 + tid]));
        zsh[tid] = mean * (1.f / KP1);
        zsh[HD + tid] = mx;
    }

    // ---------- P4: conv2: acc = b2 + Hs@Wroot2 + sum_c chunkAgg@Wrel2 ----------
    const int tr = tid >> 5, tc = tid & 31;     // 16 row-groups x 32 col-groups
    const int i0 = tr * 7, j0 = tc * 4;
    const float4* Wrel2v  = (const float4*)Wrel2;
    const float4* Wroot2v = (const float4*)Wroot2;

    float acc[7][4];
    {
        float4 bv = ((const float4*)b2)[tc];
#pragma unroll
        for (int r = 0; r < 7; ++r) { acc[r][0] = bv.x; acc[r][1] = bv.y; acc[r][2] = bv.z; acc[r][3] = bv.w; }
    }
    // root pass (rows padded to 112: no guards)
    for (int k0 = 0; k0 < HD; k0 += 4) {
#pragma unroll
        for (int ku = 0; ku < 4; ++ku) {
            int k = k0 + ku;
            float4 w = Wroot2v[k * 32 + tc];
#pragma unroll
            for (int r = 0; r < 7; ++r) {
                float a = Hs[(i0 + r) * HD + k];
                acc[r][0] += a * w.x; acc[r][1] += a * w.y; acc[r][2] += a * w.z; acc[r][3] += a * w.w;
            }
        }
    }
    // rel pass: 4 chunks of 32 columns, CB padded to 112 rows
    for (int c = 0; c < 4; ++c) {
        __syncthreads();                     // prior CB readers done
        for (int t = tid; t < NNP * 32; t += NT) CB[t] = 0.f;
        __syncthreads();
        {
            const int jj = tid & 31, eg2 = tid >> 5;   // 16 edges in flight
            const int cb = c * 32 + jj;
            for (int e = eg2; e < EPG; e += 16) {
                unsigned int p = se[e];
                int sl = (int)(p & 0xffffu), dl = (int)(p >> 16);
                atomicAdd(&CB[dl * 32 + jj], Hs[sl * HD + cb]);
            }
        }
        __syncthreads();
#pragma unroll 4
        for (int kk = 0; kk < 32; ++kk) {
            float4 w = Wrel2v[(c * 32 + kk) * 32 + tc];
#pragma unroll
            for (int r = 0; r < 7; ++r) {
                float a = CB[(i0 + r) * 32 + kk];
                acc[r][0] += a * w.x; acc[r][1] += a * w.y; acc[r][2] += a * w.z; acc[r][3] += a * w.w;
            }
        }
    }
    __syncthreads();                          // all readers of Hs done
    // write h2 = relu(acc) into Hs (pad rows written, never read)
#pragma unroll
    for (int r = 0; r < 7; ++r) {
        float4 v;
        v.x = fmaxf(acc[r][0], 0.f); v.y = fmaxf(acc[r][1], 0.f);
        v.z = fmaxf(acc[r][2], 0.f); v.w = fmaxf(acc[r][3], 0.f);
        *(float4*)&Hs[(i0 + r) * HD + j0] = v;
    }
    __syncthreads();

    // ---------- P5: pool2 + readout2 ----------
    if (tid < 400) {
        const int row = tid >> 2, q = tid & 3;
        float d = 0.f;
        for (int kk = 0; kk < 32; ++kk) {
            int k = q * 32 + ((kk + tid) & 31);
            d += Hs[row * HD + k] * p2s[k];
        }
        d += __shfl_xor(d, 1);
        d += __shfl_xor(d, 2);
        if (q == 0) sc[row] = (mk1[row] > 0.f) ? tanhf(d * inv[1]) : -1e30f;
    }
    __syncthreads();
    if (tid < NN) {
        float si = sc[tid]; int cnt = 0;
        for (int j2 = 0; j2 < NN; ++j2) cnt += (sc[j2] > si) ? 1 : 0;
        mk2[tid] = (mk1[tid] > 0.f && cnt < KP2) ? 1.f : 0.f;
    }
    __syncthreads();
    for (int o = tid; o < NN * HD; o += NT) { int i = o >> 7; Hs[o] *= sc[i] * mk2[i]; }
    __syncthreads();
    {
        const int col = tid & 127, ch = tid >> 7;
        float mean = 0.f, mx = -1e30f;
        for (int i = ch * 25; i < ch * 25 + 25; ++i) {
            float v = Hs[i * HD + col];
            mean += v;
            if (mk2[i] > 0.f && v > mx) mx = v;
        }
        zrd[tid] = mean; CB[tid] = mx;
    }
    __syncthreads();
    if (tid < HD) {
        float mean = zrd[tid] + zrd[128 + tid] + zrd[256 + tid] + zrd[384 + tid];
        float mx = fmaxf(fmaxf(CB[tid], CB[128 + tid]), fmaxf(CB[256 + tid], CB[384 + tid]));
        zsh[tid] += mean * (1.f / KP2);
        zsh[HD + tid] += mx;
    }
    __syncthreads();

    // ---------- P6: MLP + log_softmax (z1 -> CB[0:128], z2 -> CB[256:288]) ----------
    {   // l1: 256 -> 128, k split over 4 chunks of 64
        const int j = tid & 127, q = tid >> 7;
        float a = 0.f;
        for (int kk = 0; kk < 64; ++kk) {
            int k = q * 64 + kk;
            a += zsh[k] * l1w[k * HD + j];
        }
        zrd[tid] = a;
    }
    __syncthreads();
    if (tid < HD)
        CB[tid] = fmaxf(zrd[tid] + zrd[128 + tid] + zrd[256 + tid] + zrd[384 + tid] + l1b[tid], 0.f);
    __syncthreads();
    if (tid < 256) {   // l2: 128 -> 32, k split over 8 chunks of 16
        const int o = tid & 31, q = tid >> 5;
        float a = 0.f;
        for (int kk = 0; kk < 16; ++kk) {
            int k = q * 16 + kk;
            a += CB[k] * l2w[k * 32 + o];
        }
        zrd[tid] = a;
    }
    __syncthreads();
    if (tid < 32) {
        float v = l2b[tid];
#pragma unroll
        for (int q = 0; q < 8; ++q) v += zrd[q * 32 + tid];
        CB[256 + tid] = fmaxf(v, 0.f);
    }
    __syncthreads();
    if (tid == 0) {
        float o0 = l3b[0], o1 = l3b[1];
        for (int k = 0; k < 32; ++k) {
            float v = CB[256 + k];
            o0 += v * l3w[2 * k];
            o1 += v * l3w[2 * k + 1];
        }
        float m = fmaxf(o0, o1);
        float l = m + logf(expf(o0 - m) + expf(o1 - m));
        out[g * 2 + 0] = o0 - l;
        out[g * 2 + 1] = o1 - l;
    }
}

extern "C" void kernel_launch(void* const* d_in, const int* in_sizes, int n_in,
                              void* d_out, int out_size, void* d_ws, size_t ws_size,
                              hipStream_t stream)
{
    const float* x      = (const float*)d_in[0];
    const int*   ei     = (const int*)d_in[1];
    const float* Wrel1  = (const float*)d_in[2];
    const float* Wroot1 = (const float*)d_in[3];
    const float* b1     = (const float*)d_in[4];
    const float* p1     = (const float*)d_in[5];
    const float* Wrel2  = (const float*)d_in[6];
    const float* Wroot2 = (const float*)d_in[7];
    const float* b2     = (const float*)d_in[8];
    const float* p2     = (const float*)d_in[9];
    const float* l1w    = (const float*)d_in[10];
    const float* l1b    = (const float*)d_in[11];
    const float* l2w    = (const float*)d_in[12];
    const float* l2b    = (const float*)d_in[13];
    const float* l3w    = (const float*)d_in[14];
    const float* l3b    = (const float*)d_in[15];
    float* out = (float*)d_out;

    (void)hipFuncSetAttribute((const void*)fused_gnn,
                              hipFuncAttributeMaxDynamicSharedMemorySize, SMEM_BYTES);

    fused_gnn<<<dim3(NB), dim3(NT), SMEM_BYTES, stream>>>(
        x, ei, Wrel1, Wroot1, b1, p1, Wrel2, Wroot2, b2, p2,
        l1w, l1b, l2w, l2b, l3w, l3b, out);
}

// Round 5
// 238.968 us; speedup vs baseline: 6.5123x; 3.6195x over previous
//
#include <hip/hip_runtime.h>
#include <math.h>

#define NB 1000      // graphs
#define NN 100       // nodes per graph
#define NNP 112      // padded rows (16 row-groups * 7)
#define EPG 1000     // edges per graph
#define FIN 14
#define HD 128
#define KP1 80
#define KP2 64
#define NT 512       // threads per block

// LDS float offsets
#define O_HS   0                        // [112][128] = 14336
#define O_CB   14336                    // [112][32] = 3584 (alias xg[0:1600], ag[1600:3200]; pads 3200:3584)
#define O_SS   17920                    // 1000 ints: CSR sorted sources
#define O_RP   18920                    // 104 ints: rowptr
#define O_SC   19024                    // 100
#define O_MK1  19124                    // 100
#define O_MK2  19224                    // 100
#define O_P1   19324                    // 128
#define O_P2   19452                    // 128
#define O_ZSH  19580                    // 256
#define O_ZRD  19836                    // 512 floats (ints deg[0:128], pos[128:228] during CSR build)
#define O_INV  20348                    // 2
#define NSM    20350
#define SMEM_BYTES (NSM * 4)            // 81400 B -> 2 blocks/CU (160 KB pool)

__global__ __launch_bounds__(NT, 4) void fused_gnn(
    const float* __restrict__ x, const int* __restrict__ ei,
    const float* __restrict__ Wrel1, const float* __restrict__ Wroot1,
    const float* __restrict__ b1, const float* __restrict__ p1,
    const float* __restrict__ Wrel2, const float* __restrict__ Wroot2,
    const float* __restrict__ b2, const float* __restrict__ p2,
    const float* __restrict__ l1w, const float* __restrict__ l1b,
    const float* __restrict__ l2w, const float* __restrict__ l2b,
    const float* __restrict__ l3w, const float* __restrict__ l3b,
    float* __restrict__ out)
{
    extern __shared__ float smf[];
    float* Hs  = smf + O_HS;
    float* CB  = smf + O_CB;
    float* xg  = CB;                 // [100][16] (cols 14,15 zero)
    float* ag  = CB + 1600;          // [100][16]
    int*   ssrc = (int*)(smf + O_SS);
    int*   rowptr = (int*)(smf + O_RP);
    float* sc  = smf + O_SC;
    float* mk1 = smf + O_MK1;
    float* mk2 = smf + O_MK2;
    float* p1s = smf + O_P1;
    float* p2s = smf + O_P2;
    float* zsh = smf + O_ZSH;
    float* zrd = smf + O_ZRD;
    int*   zdi = (int*)(smf + O_ZRD);   // deg[0:128] / pos[128:228] during build
    float* inv = smf + O_INV;

    const int tid = threadIdx.x;
    const int g = blockIdx.x;
    const int bn = g * NN;
    const int* srcp = ei + g * EPG;
    const int* dstp = ei + NB * EPG + g * EPG;

    // ---------- P0a: stage xg/ag, zero pads, p vectors + norms, zero deg ----------
    for (int t = tid; t < 1600; t += NT) {
        int i = t >> 4, f = t & 15;
        xg[t] = (f < FIN) ? x[bn * FIN + i * FIN + f] : 0.f;
        ag[t] = 0.f;
    }
    if (tid < 384) CB[3200 + tid] = 0.f;              // CB pad rows 100..111
    for (int t = tid; t < (NNP - NN) * HD; t += NT) Hs[NN * HD + t] = 0.f;
    if (tid < 128) { p1s[tid] = p1[tid]; p2s[tid] = p2[tid]; zdi[tid] = 0; }
    if (tid >= 256 && tid < 320) {
        int l = tid - 256;
        float a = p1[l], b = p1[l + 64];
        float v = a * a + b * b;
        for (int s = 1; s < 64; s <<= 1) v += __shfl_xor(v, s);
        if (l == 0) inv[0] = rsqrtf(v);
    } else if (tid >= 320 && tid < 384) {
        int l = tid - 320;
        float a = p2[l], b = p2[l + 64];
        float v = a * a + b * b;
        for (int s = 1; s < 64; s <<= 1) v += __shfl_xor(v, s);
        if (l == 0) inv[1] = rsqrtf(v);
    }
    __syncthreads();

    // ---------- P0b: CSR build — count ----------
    for (int e = tid; e < EPG; e += NT) {
        int dl = dstp[e] - bn;
        atomicAdd(&zdi[dl], 1);
    }
    __syncthreads();
    // ---------- P0c: exclusive scan via wave shfl (deg[0:128] -> rowptr) ----------
    if (tid < 64) {
        int a = zdi[tid], b = zdi[tid + 64];
        for (int off = 1; off < 64; off <<= 1) { int t = __shfl_up(a, off); if (tid >= off) a += t; }
        int totA = __shfl(a, 63);
        for (int off = 1; off < 64; off <<= 1) { int t = __shfl_up(b, off); if (tid >= off) b += t; }
        b += totA;
        rowptr[tid + 1] = a;          // inclusive -> rowptr[i+1]
        if (tid + 65 <= 103) rowptr[tid + 65] = b;
        if (tid == 0) rowptr[0] = 0;
    }
    __syncthreads();
    if (tid < NN) zdi[128 + tid] = rowptr[tid];       // pos cursors
    __syncthreads();
    // ---------- P0d: CSR scatter ----------
    for (int e = tid; e < EPG; e += NT) {
        int sl = srcp[e] - bn;
        int dl = dstp[e] - bn;
        int slot = atomicAdd(&zdi[128 + dl], 1);
        ssrc[slot] = sl;
    }
    __syncthreads();

    // ---------- P1: conv1 agg via CSR: ag[i][f] = sum_in-edges xg[src][f] ----------
    {
        const int f = tid & 15;
        if (f < FIN) {
            for (int i = tid >> 4; i < NN; i += 32) {
                int s0 = rowptr[i], s1 = rowptr[i + 1];
                float s = 0.f;
                for (int sl0 = s0; sl0 < s1; ++sl0)
                    s += xg[ssrc[sl0] * 16 + f];
                ag[i * 16 + f] = s;
            }
        }
    }
    __syncthreads();

    // ---------- P2: h1 = relu(ag@Wrel1 + xg@Wroot1 + b1) ----------
    {
        const int j = tid & 127;
        float wr[FIN], wo[FIN];
#pragma unroll
        for (int k = 0; k < FIN; ++k) { wr[k] = Wrel1[k * HD + j]; wo[k] = Wroot1[k * HD + j]; }
        const float bb = b1[j];
        for (int i = tid >> 7; i < NN; i += 4) {
            float s = bb;
#pragma unroll
            for (int k = 0; k < FIN; ++k)
                s += ag[i * 16 + k] * wr[k] + xg[i * 16 + k] * wo[k];
            Hs[i * HD + j] = fmaxf(s, 0.f);
        }
    }
    __syncthreads();

    // ---------- P3: pool1 score (4 lanes/row, skewed) + top-80 + scale + readout1 ----------
    if (tid < 400) {
        const int row = tid >> 2, q = tid & 3;
        float d = 0.f;
        for (int kk = 0; kk < 32; ++kk) {
            int k = q * 32 + ((kk + tid) & 31);
            d += Hs[row * HD + k] * p1s[k];
        }
        d += __shfl_xor(d, 1);
        d += __shfl_xor(d, 2);
        if (q == 0) sc[row] = tanhf(d * inv[0]);
    }
    __syncthreads();
    if (tid < NN) {
        float si = sc[tid]; int cnt = 0;
        for (int j2 = 0; j2 < NN; ++j2) cnt += (sc[j2] > si) ? 1 : 0;
        mk1[tid] = (cnt < KP1) ? 1.f : 0.f;
    }
    __syncthreads();
    for (int o = tid; o < NN * HD; o += NT) { int i = o >> 7; Hs[o] *= sc[i] * mk1[i]; }
    __syncthreads();
    {
        const int col = tid & 127, ch = tid >> 7;
        float mean = 0.f, mx = -1e30f;
        for (int i = ch * 25; i < ch * 25 + 25; ++i) {
            float v = Hs[i * HD + col];
            mean += v;
            if (mk1[i] > 0.f && v > mx) mx = v;
        }
        zrd[tid] = mean; CB[tid] = mx;
    }
    __syncthreads();
    if (tid < HD) {
        float mean = zrd[tid] + zrd[128 + tid] + zrd[256 + tid] + zrd[384 + tid];
        float mx = fmaxf(fmaxf(CB[tid], CB[128 + tid]), fmaxf(CB[256 + tid], CB[384 + tid]));
        zsh[tid] = mean * (1.f / KP1);
        zsh[HD + tid] = mx;
    }

    // ---------- P4: conv2: acc = b2 + Hs@Wroot2 + sum_c CSRagg@Wrel2 ----------
    const int tr = tid >> 5, tc = tid & 31;     // 16 row-groups x 32 col-groups
    const int i0 = tr * 7, j0 = tc * 4;
    const float4* Wrel2v  = (const float4*)Wrel2;
    const float4* Wroot2v = (const float4*)Wroot2;

    float acc[7][4];
    {
        float4 bv = ((const float4*)b2)[tc];
#pragma unroll
        for (int r = 0; r < 7; ++r) { acc[r][0] = bv.x; acc[r][1] = bv.y; acc[r][2] = bv.z; acc[r][3] = bv.w; }
    }
    // root pass: unroll-8 batched weight loads, b128 LDS reads
    for (int k0 = 0; k0 < HD; k0 += 8) {
        float4 w[8];
#pragma unroll
        for (int u = 0; u < 8; ++u) w[u] = Wroot2v[(k0 + u) * 32 + tc];
#pragma unroll
        for (int r = 0; r < 7; ++r) {
            float4 a0 = *(const float4*)&Hs[(i0 + r) * HD + k0];
            float4 a1 = *(const float4*)&Hs[(i0 + r) * HD + k0 + 4];
            acc[r][0] += a0.x * w[0].x + a0.y * w[1].x + a0.z * w[2].x + a0.w * w[3].x
                       + a1.x * w[4].x + a1.y * w[5].x + a1.z * w[6].x + a1.w * w[7].x;
            acc[r][1] += a0.x * w[0].y + a0.y * w[1].y + a0.z * w[2].y + a0.w * w[3].y
                       + a1.x * w[4].y + a1.y * w[5].y + a1.z * w[6].y + a1.w * w[7].y;
            acc[r][2] += a0.x * w[0].z + a0.y * w[1].z + a0.z * w[2].z + a0.w * w[3].z
                       + a1.x * w[4].z + a1.y * w[5].z + a1.z * w[6].z + a1.w * w[7].z;
            acc[r][3] += a0.x * w[0].w + a0.y * w[1].w + a0.z * w[2].w + a0.w * w[3].w
                       + a1.x * w[4].w + a1.y * w[5].w + a1.z * w[6].w + a1.w * w[7].w;
        }
    }
    // rel pass: 4 chunks of 32 cols; CSR gather (no atomics) then unroll-8 FMA
    for (int c = 0; c < 4; ++c) {
        __syncthreads();                     // prior CB readers done
        {
            const int jj = tid & 31;
            const int cb = c * 32 + jj;
            for (int i = tid >> 5; i < NN; i += 16) {
                int s0 = rowptr[i], s1 = rowptr[i + 1];
                float s = 0.f;
                for (int sl0 = s0; sl0 < s1; ++sl0)
                    s += Hs[ssrc[sl0] * HD + cb];
                CB[i * 32 + jj] = s;
            }
        }
        __syncthreads();
        for (int kk0 = 0; kk0 < 32; kk0 += 8) {
            float4 w[8];
#pragma unroll
            for (int u = 0; u < 8; ++u) w[u] = Wrel2v[(c * 32 + kk0 + u) * 32 + tc];
#pragma unroll
            for (int r = 0; r < 7; ++r) {
                float4 a0 = *(const float4*)&CB[(i0 + r) * 32 + kk0];
                float4 a1 = *(const float4*)&CB[(i0 + r) * 32 + kk0 + 4];
                acc[r][0] += a0.x * w[0].x + a0.y * w[1].x + a0.z * w[2].x + a0.w * w[3].x
                           + a1.x * w[4].x + a1.y * w[5].x + a1.z * w[6].x + a1.w * w[7].x;
                acc[r][1] += a0.x * w[0].y + a0.y * w[1].y + a0.z * w[2].y + a0.w * w[3].y
                           + a1.x * w[4].y + a1.y * w[5].y + a1.z * w[6].y + a1.w * w[7].y;
                acc[r][2] += a0.x * w[0].z + a0.y * w[1].z + a0.z * w[2].z + a0.w * w[3].z
                           + a1.x * w[4].z + a1.y * w[5].z + a1.z * w[6].z + a1.w * w[7].z;
                acc[r][3] += a0.x * w[0].w + a0.y * w[1].w + a0.z * w[2].w + a0.w * w[3].w
                           + a1.x * w[4].w + a1.y * w[5].w + a1.z * w[6].w + a1.w * w[7].w;
            }
        }
    }
    __syncthreads();                          // all readers of Hs done
#pragma unroll
    for (int r = 0; r < 7; ++r) {
        float4 v;
        v.x = fmaxf(acc[r][0], 0.f); v.y = fmaxf(acc[r][1], 0.f);
        v.z = fmaxf(acc[r][2], 0.f); v.w = fmaxf(acc[r][3], 0.f);
        *(float4*)&Hs[(i0 + r) * HD + j0] = v;
    }
    __syncthreads();

    // ---------- P5: pool2 + readout2 ----------
    if (tid < 400) {
        const int row = tid >> 2, q = tid & 3;
        float d = 0.f;
        for (int kk = 0; kk < 32; ++kk) {
            int k = q * 32 + ((kk + tid) & 31);
            d += Hs[row * HD + k] * p2s[k];
        }
        d += __shfl_xor(d, 1);
        d += __shfl_xor(d, 2);
        if (q == 0) sc[row] = (mk1[row] > 0.f) ? tanhf(d * inv[1]) : -1e30f;
    }
    __syncthreads();
    if (tid < NN) {
        float si = sc[tid]; int cnt = 0;
        for (int j2 = 0; j2 < NN; ++j2) cnt += (sc[j2] > si) ? 1 : 0;
        mk2[tid] = (mk1[tid] > 0.f && cnt < KP2) ? 1.f : 0.f;
    }
    __syncthreads();
    for (int o = tid; o < NN * HD; o += NT) { int i = o >> 7; Hs[o] *= sc[i] * mk2[i]; }
    __syncthreads();
    {
        const int col = tid & 127, ch = tid >> 7;
        float mean = 0.f, mx = -1e30f;
        for (int i = ch * 25; i < ch * 25 + 25; ++i) {
            float v = Hs[i * HD + col];
            mean += v;
            if (mk2[i] > 0.f && v > mx) mx = v;
        }
        zrd[tid] = mean; CB[tid] = mx;
    }
    __syncthreads();
    if (tid < HD) {
        float mean = zrd[tid] + zrd[128 + tid] + zrd[256 + tid] + zrd[384 + tid];
        float mx = fmaxf(fmaxf(CB[tid], CB[128 + tid]), fmaxf(CB[256 + tid], CB[384 + tid]));
        zsh[tid] += mean * (1.f / KP2);
        zsh[HD + tid] += mx;
    }
    __syncthreads();

    // ---------- P6: MLP + log_softmax (z1 -> CB[0:128], z2 -> CB[256:288]) ----------
    {   // l1: 256 -> 128, k split over 4 chunks of 64
        const int j = tid & 127, q = tid >> 7;
        float a = 0.f;
        for (int kk = 0; kk < 64; ++kk) {
            int k = q * 64 + kk;
            a += zsh[k] * l1w[k * HD + j];
        }
        zrd[tid] = a;
    }
    __syncthreads();
    if (tid < HD)
        CB[tid] = fmaxf(zrd[tid] + zrd[128 + tid] + zrd[256 + tid] + zrd[384 + tid] + l1b[tid], 0.f);
    __syncthreads();
    if (tid < 256) {   // l2: 128 -> 32, k split over 8 chunks of 16
        const int o = tid & 31, q = tid >> 5;
        float a = 0.f;
        for (int kk = 0; kk < 16; ++kk) {
            int k = q * 16 + kk;
            a += CB[k] * l2w[k * 32 + o];
        }
        zrd[tid] = a;
    }
    __syncthreads();
    if (tid < 32) {
        float v = l2b[tid];
#pragma unroll
        for (int q = 0; q < 8; ++q) v += zrd[q * 32 + tid];
        CB[256 + tid] = fmaxf(v, 0.f);
    }
    __syncthreads();
    if (tid == 0) {
        float o0 = l3b[0], o1 = l3b[1];
        for (int k = 0; k < 32; ++k) {
            float v = CB[256 + k];
            o0 += v * l3w[2 * k];
            o1 += v * l3w[2 * k + 1];
        }
        float m = fmaxf(o0, o1);
        float l = m + logf(expf(o0 - m) + expf(o1 - m));
        out[g * 2 + 0] = o0 - l;
        out[g * 2 + 1] = o1 - l;
    }
}

extern "C" void kernel_launch(void* const* d_in, const int* in_sizes, int n_in,
                              void* d_out, int out_size, void* d_ws, size_t ws_size,
                              hipStream_t stream)
{
    const float* x      = (const float*)d_in[0];
    const int*   ei     = (const int*)d_in[1];
    const float* Wrel1  = (const float*)d_in[2];
    const float* Wroot1 = (const float*)d_in[3];
    const float* b1     = (const float*)d_in[4];
    const float* p1     = (const float*)d_in[5];
    const float* Wrel2  = (const float*)d_in[6];
    const float* Wroot2 = (const float*)d_in[7];
    const float* b2     = (const float*)d_in[8];
    const float* p2     = (const float*)d_in[9];
    const float* l1w    = (const float*)d_in[10];
    const float* l1b    = (const float*)d_in[11];
    const float* l2w    = (const float*)d_in[12];
    const float* l2b    = (const float*)d_in[13];
    const float* l3w    = (const float*)d_in[14];
    const float* l3b    = (const float*)d_in[15];
    float* out = (float*)d_out;

    (void)hipFuncSetAttribute((const void*)fused_gnn,
                              hipFuncAttributeMaxDynamicSharedMemorySize, SMEM_BYTES);

    fused_gnn<<<dim3(NB), dim3(NT), SMEM_BYTES, stream>>>(
        x, ei, Wrel1, Wroot1, b1, p1, Wrel2, Wroot2, b2, p2,
        l1w, l1b, l2w, l2b, l3w, l3b, out);
}